// Round 4
// baseline (461.530 us; speedup 1.0000x reference)
//
#include <hip/hip_runtime.h>

// Problem constants (match reference)
#define HP  1026                 // H+2
#define WP  2050                 // W+2
#define GRID_F (HP*WP)           // 2,103,300 cells = 8.41 MB fp32

// ws layout (floats)
#define IDX_OFF   2103360        // int grid, 64-aligned
#define STATS_OFF 4206720        // 54 moment accumulators, done ctr at +56
#define SCALE_OFF 4206784
#define SHIFT_OFF 4206848

typedef float fvec4 __attribute__((ext_vector_type(4)));

// ---------------------------------------------------------------- scatter
// Pair-vectorized: int4 coord load (2 points), float2 feats load.
__global__ __launch_bounds__(256) void scatter_k(
    const float2* __restrict__ feats2, const int4* __restrict__ coords2,
    float* __restrict__ grid, int* __restrict__ idxg, int Npair, int N)
{
    int i = blockIdx.x * 256 + threadIdx.x;
    if (i >= Npair) return;
    int4   c = coords2[i];
    float2 f = feats2[i];
    int cell0 = (c.x + 1) * WP + (c.y + 1);
    int cell1 = (c.z + 1) * WP + (c.w + 1);
    grid[cell0] = f.x;  idxg[cell0] = 2 * i + 1;
    grid[cell1] = f.y;  idxg[cell1] = 2 * i + 2;
    if (i == 0 && (N & 1)) {                 // odd-N tail (not hit for N=1e6)
        const int2* cc = (const int2*)coords2;
        const float* ff = (const float*)feats2;
        int2 cl = cc[N - 1];
        int cell = (cl.x + 1) * WP + (cl.y + 1);
        grid[cell] = ff[N - 1]; idxg[cell] = N;
    }
}

// ---------------------------------------------------------- stats+finalize
// Dense row-order moments (9 sums + 45 upper-tri second moments), block
// partials via wave shuffle + one atomic per value; LAST block (device
// atomic done-counter) folds moments -> per-channel scale/shift.
__global__ __launch_bounds__(256) void stats_fused_k(
    const float* __restrict__ grid, const int* __restrict__ idxg,
    float* __restrict__ stats, int* __restrict__ done,
    const float* __restrict__ w, const float* __restrict__ gamma,
    const float* __restrict__ beta,
    float* __restrict__ scale, float* __restrict__ shift, int N)
{
    const int off[9] = {-WP-1, -WP, -WP+1, -1, 0, 1, WP-1, WP, WP+1};
    float acc[54];
    #pragma unroll
    for (int j = 0; j < 54; ++j) acc[j] = 0.f;

    int t = threadIdx.x;
    int stride = gridDim.x * blockDim.x;
    for (int c = blockIdx.x * blockDim.x + t; c < GRID_F; c += stride) {
        if (idxg[c] > 0) {
            float p[9];
            #pragma unroll
            for (int k = 0; k < 9; ++k) p[k] = grid[c + off[k]];
            #pragma unroll
            for (int k = 0; k < 9; ++k) acc[k] += p[k];
            int u = 9;
            #pragma unroll
            for (int k = 0; k < 9; ++k)
                #pragma unroll
                for (int l = k; l < 9; ++l) acc[u++] += p[k] * p[l];
        }
    }

    __shared__ float part[4][54];
    int wave = t >> 6, lane = t & 63;
    #pragma unroll
    for (int j = 0; j < 54; ++j) {
        float v = acc[j];
        #pragma unroll
        for (int d = 32; d > 0; d >>= 1) v += __shfl_down(v, d, 64);
        if (lane == 0) part[wave][j] = v;
    }
    __syncthreads();
    if (t < 54) {
        float v = part[0][t] + part[1][t] + part[2][t] + part[3][t];
        atomicAdd(&stats[t], v);
    }
    __threadfence();                          // make adds device-visible
    __syncthreads();

    __shared__ int isLast;
    if (t == 0) isLast = (atomicAdd(done, 1) == (int)gridDim.x - 1);
    __syncthreads();
    if (!isLast) return;

    __shared__ float st[54];
    if (t < 54) st[t] = atomicAdd(&stats[t], 0.0f);   // coherent read
    __syncthreads();
    if (t < 64) {
        float invN = 1.0f / (float)N;
        float wc[9];
        #pragma unroll
        for (int k = 0; k < 9; ++k) wc[k] = w[k * 64 + t];
        float mean = 0.f;
        #pragma unroll
        for (int k = 0; k < 9; ++k) mean += st[k] * invN * wc[k];
        float e2 = 0.f;
        int u = 9;
        #pragma unroll
        for (int k = 0; k < 9; ++k)
            #pragma unroll
            for (int l = k; l < 9; ++l) {
                float mm = st[u++] * invN;
                e2 += (k == l ? 1.f : 2.f) * wc[k] * wc[l] * mm;
            }
        float var = e2 - mean * mean;
        float sc = gamma[t] * rsqrtf(var + 1e-5f);
        scale[t] = sc;
        shift[t] = beta[t] - mean * sc;
    }
}

// ---------------------------------------------------------------- output
// Dense tile pass, 256 cells/block, LDS compaction. Weights + BN regs
// hoisted (q = t&15 loop-invariant). Regular stores (L2 write-back batches
// the scattered 256B chunks; NT was bypassing that).
__global__ __launch_bounds__(256) void out_dense_k(
    const float* __restrict__ grid, const int* __restrict__ idxg,
    const float* __restrict__ w, const float* __restrict__ scale,
    const float* __restrict__ shift, float* __restrict__ out)
{
    __shared__ float w_s[576];
    __shared__ float sc_s[64], sh_s[64];
    __shared__ float nb_s[9][256];
    __shared__ int   cell_s[256];
    __shared__ int   oidx_s[256];
    __shared__ int   cnt;

    int t = threadIdx.x;
    if (t == 0) cnt = 0;
    w_s[t]       = w[t];
    w_s[t + 256] = w[t + 256];
    if (t < 64) {
        w_s[t + 512] = w[t + 512];
        sc_s[t] = scale[t];
        sh_s[t] = shift[t];
    }
    __syncthreads();                           // w_s/sc/sh + cnt=0 visible

    int c = blockIdx.x * 256 + t;
    if (c < GRID_F) {
        int idx = idxg[c];
        if (idx > 0) {
            int p = atomicAdd(&cnt, 1);
            cell_s[p] = c;
            oidx_s[p] = idx - 1;
        }
    }
    __syncthreads();
    int M = cnt;
    if (M == 0) return;

    const int off[9] = {-WP-1, -WP, -WP+1, -1, 0, 1, WP-1, WP, WP+1};
    if (t < M) {
        int base = cell_s[t];
        #pragma unroll
        for (int k = 0; k < 9; ++k) nb_s[k][t] = grid[base + off[k]];
    }

    // hoist loop-invariant weight / BN fragments (w_s valid since sync #1)
    int q = t & 15;
    const fvec4* w4 = (const fvec4*)w_s;       // [9][16]
    fvec4 wv[9];
    #pragma unroll
    for (int k = 0; k < 9; ++k) wv[k] = w4[k * 16 + q];
    fvec4 sc4 = ((const fvec4*)sc_s)[q];
    fvec4 sh4 = ((const fvec4*)sh_s)[q];
    __syncthreads();                           // nb_s ready

    fvec4* out4 = (fvec4*)out;
    for (int u = t; u < 16 * M; u += 256) {
        int pt = u >> 4;
        fvec4 acc = {0.f, 0.f, 0.f, 0.f};
        #pragma unroll
        for (int k = 0; k < 9; ++k)
            acc += nb_s[k][pt] * wv[k];
        acc = acc * sc4 + sh4;
        acc.x = fmaxf(acc.x, 0.f);
        acc.y = fmaxf(acc.y, 0.f);
        acc.z = fmaxf(acc.z, 0.f);
        acc.w = fmaxf(acc.w, 0.f);
        out4[(long)oidx_s[pt] * 16 + q] = acc;
    }
}

// ---------------------------------------------------------------- launch
extern "C" void kernel_launch(void* const* d_in, const int* in_sizes, int n_in,
                              void* d_out, int out_size, void* d_ws, size_t ws_size,
                              hipStream_t stream)
{
    const float* feats  = (const float*)d_in[0];
    const float* weight = (const float*)d_in[1];   // [9][1][64]
    const float* gamma  = (const float*)d_in[2];
    const float* beta   = (const float*)d_in[3];
    const int*   coords = (const int*)d_in[4];     // [N][2] (y,x)
    float*       out    = (float*)d_out;
    int N = in_sizes[0];                           // C_IN == 1

    float* ws    = (float*)d_ws;
    float* grid  = ws;
    int*   idxg  = (int*)(ws + IDX_OFF);
    float* stats = ws + STATS_OFF;
    int*   done  = (int*)(ws + STATS_OFF + 56);
    float* scale = ws + SCALE_OFF;
    float* shift = ws + SHIFT_OFF;

    // zero grid + idx grid + stats/done (ws is poisoned 0xAA each call)
    (void)hipMemsetAsync(d_ws, 0, (size_t)(STATS_OFF + 64) * sizeof(float), stream);

    int Npair = N >> 1;
    scatter_k    <<<(Npair + 255) / 256, 256, 0, stream>>>(
        (const float2*)feats, (const int4*)coords, grid, idxg, Npair, N);
    stats_fused_k<<<2048, 256, 0, stream>>>(
        grid, idxg, stats, done, weight, gamma, beta, scale, shift, N);
    out_dense_k  <<<(GRID_F + 255) / 256, 256, 0, stream>>>(
        grid, idxg, weight, scale, shift, out);
}

// Round 5
// 377.890 us; speedup vs baseline: 1.2213x; 1.2213x over previous
//
#include <hip/hip_runtime.h>

// Problem constants (match reference)
#define HP  1026                 // H+2
#define WP  2050                 // W+2
#define GRID_F (HP*WP)           // 2,103,300 cells = 8.41 MB fp32

// ws layout (floats)
#define IDX_OFF   2103360        // int grid, 64-aligned
#define STATS_OFF 4206720        // 54 moment accumulators
#define SCALE_OFF 4206784
#define SHIFT_OFF 4206848

typedef float fvec4 __attribute__((ext_vector_type(4)));

// ---------------------------------------------------------------- scatter
// Pair-vectorized: int4 coord load (2 points), float2 feats load.
__global__ __launch_bounds__(256) void scatter_k(
    const float2* __restrict__ feats2, const int4* __restrict__ coords2,
    float* __restrict__ grid, int* __restrict__ idxg, int Npair, int N)
{
    int i = blockIdx.x * 256 + threadIdx.x;
    if (i >= Npair) return;
    int4   c = coords2[i];
    float2 f = feats2[i];
    int cell0 = (c.x + 1) * WP + (c.y + 1);
    int cell1 = (c.z + 1) * WP + (c.w + 1);
    grid[cell0] = f.x;  idxg[cell0] = 2 * i + 1;
    grid[cell1] = f.y;  idxg[cell1] = 2 * i + 2;
    if (i == 0 && (N & 1)) {                 // odd-N tail (not hit for N=1e6)
        const int2* cc = (const int2*)coords2;
        const float* ff = (const float*)feats2;
        int2 cl = cc[N - 1];
        int cell = (cl.x + 1) * WP + (cl.y + 1);
        grid[cell] = ff[N - 1]; idxg[cell] = N;
    }
}

// ---------------------------------------------------------------- stats
// Dense row-order pass: s[k] (9) + upper-tri second moments M[k][l] (45).
__global__ __launch_bounds__(256) void stats_dense_k(
    const float* __restrict__ grid, const int* __restrict__ idxg,
    float* __restrict__ stats)
{
    const int off[9] = {-WP-1, -WP, -WP+1, -1, 0, 1, WP-1, WP, WP+1};
    float acc[54];
    #pragma unroll
    for (int j = 0; j < 54; ++j) acc[j] = 0.f;

    int stride = gridDim.x * blockDim.x;
    for (int c = blockIdx.x * blockDim.x + threadIdx.x; c < GRID_F; c += stride) {
        if (idxg[c] > 0) {                    // active center
            float p[9];
            #pragma unroll
            for (int k = 0; k < 9; ++k) p[k] = grid[c + off[k]];
            #pragma unroll
            for (int k = 0; k < 9; ++k) acc[k] += p[k];
            int t = 9;
            #pragma unroll
            for (int k = 0; k < 9; ++k)
                #pragma unroll
                for (int l = k; l < 9; ++l) acc[t++] += p[k] * p[l];
        }
    }

    __shared__ float part[4][54];
    int wave = threadIdx.x >> 6, lane = threadIdx.x & 63;
    #pragma unroll
    for (int j = 0; j < 54; ++j) {
        float v = acc[j];
        #pragma unroll
        for (int d = 32; d > 0; d >>= 1) v += __shfl_down(v, d, 64);
        if (lane == 0) part[wave][j] = v;
    }
    __syncthreads();
    if (threadIdx.x < 54) {
        float v = part[0][threadIdx.x] + part[1][threadIdx.x]
                + part[2][threadIdx.x] + part[3][threadIdx.x];
        atomicAdd(&stats[threadIdx.x], v);
    }
}

// ---------------------------------------------------------------- finalize
__global__ void finalize_k(
    const float* __restrict__ stats, const float* __restrict__ w,
    const float* __restrict__ gamma, const float* __restrict__ beta,
    float* __restrict__ scale, float* __restrict__ shift, int N)
{
    int c = threadIdx.x;                      // 0..63
    float invN = 1.0f / (float)N;
    float wc[9];
    #pragma unroll
    for (int k = 0; k < 9; ++k) wc[k] = w[k * 64 + c];
    float mean = 0.f;
    #pragma unroll
    for (int k = 0; k < 9; ++k) mean += stats[k] * invN * wc[k];
    float e2 = 0.f;
    int t = 9;
    #pragma unroll
    for (int k = 0; k < 9; ++k)
        #pragma unroll
        for (int l = k; l < 9; ++l) {
            float mm = stats[t++] * invN;
            e2 += (k == l ? 1.f : 2.f) * wc[k] * wc[l] * mm;
        }
    float var = e2 - mean * mean;
    float sc = gamma[c] * rsqrtf(var + 1e-5f);
    scale[c] = sc;
    shift[c] = beta[c] - mean * sc;
}

// ---------------------------------------------------------------- output
// Point-order: 64 points / block. Coalesced coords load, 576 scattered
// gathers from L2/L3-resident grid staged to LDS, hoisted weight/BN regs,
// then SEQUENTIAL full-line NT float4 stores (fill-like pattern, ~6.4 TB/s).
__global__ __launch_bounds__(256) void out_point_k(
    const float* __restrict__ grid, const int2* __restrict__ coords,
    const float* __restrict__ w, const float* __restrict__ scale,
    const float* __restrict__ shift, float* __restrict__ out, int N)
{
    __shared__ float w_s[576];
    __shared__ float sc_s[64], sh_s[64];
    __shared__ float nb_s[9][64];
    __shared__ int   base_s[64];

    int t  = threadIdx.x;
    int p0 = blockIdx.x * 64;

    w_s[t]       = w[t];
    w_s[t + 256] = w[t + 256];
    if (t < 64) {
        w_s[t + 512] = w[t + 512];
        sc_s[t] = scale[t];
        sh_s[t] = shift[t];
        int p  = p0 + t;
        int2 c = (p < N) ? coords[p] : make_int2(0, 0);
        base_s[t] = (c.x + 1) * WP + (c.y + 1);
    }
    __syncthreads();

    const int off[9] = {-WP-1, -WP, -WP+1, -1, 0, 1, WP-1, WP, WP+1};
    #pragma unroll
    for (int j = t; j < 576; j += 256) {       // 9 offsets * 64 points
        int k = j >> 6, pt = j & 63;
        nb_s[k][pt] = grid[base_s[pt] + off[k]];  // pad points read cell(1,1): safe
    }

    // hoist loop-invariant weight / BN fragments (w_s valid since sync #1)
    int q = t & 15;                            // channel quad, invariant over r
    const fvec4* w4 = (const fvec4*)w_s;       // [9][16]
    fvec4 wv[9];
    #pragma unroll
    for (int k = 0; k < 9; ++k) wv[k] = w4[k * 16 + q];
    fvec4 sc4 = ((const fvec4*)sc_s)[q];
    fvec4 sh4 = ((const fvec4*)sh_s)[q];
    __syncthreads();                           // nb_s ready

    fvec4* out4 = (fvec4*)out;
    long b16   = (long)blockIdx.x * 1024;      // block covers 1024 float4s
    long lim16 = (long)N * 16;

    #pragma unroll
    for (int r = 0; r < 4; ++r) {
        int idx = t + r * 256;                 // 0..1023 ; idx&15 == q
        int pt  = idx >> 4;
        fvec4 acc = {0.f, 0.f, 0.f, 0.f};
        #pragma unroll
        for (int k = 0; k < 9; ++k)
            acc += nb_s[k][pt] * wv[k];
        acc = acc * sc4 + sh4;
        acc.x = fmaxf(acc.x, 0.f);
        acc.y = fmaxf(acc.y, 0.f);
        acc.z = fmaxf(acc.z, 0.f);
        acc.w = fmaxf(acc.w, 0.f);
        long gi = b16 + idx;
        if (gi < lim16) __builtin_nontemporal_store(acc, &out4[gi]);
    }
}

// ---------------------------------------------------------------- launch
extern "C" void kernel_launch(void* const* d_in, const int* in_sizes, int n_in,
                              void* d_out, int out_size, void* d_ws, size_t ws_size,
                              hipStream_t stream)
{
    const float* feats  = (const float*)d_in[0];
    const float* weight = (const float*)d_in[1];   // [9][1][64]
    const float* gamma  = (const float*)d_in[2];
    const float* beta   = (const float*)d_in[3];
    const int*   coords = (const int*)d_in[4];     // [N][2] (y,x)
    float*       out    = (float*)d_out;
    int N = in_sizes[0];                           // C_IN == 1

    float* ws    = (float*)d_ws;
    float* grid  = ws;
    int*   idxg  = (int*)(ws + IDX_OFF);
    float* stats = ws + STATS_OFF;
    float* scale = ws + SCALE_OFF;
    float* shift = ws + SHIFT_OFF;

    // zero grid + idx grid + stats (ws is poisoned 0xAA each call)
    (void)hipMemsetAsync(d_ws, 0, (size_t)(STATS_OFF + 64) * sizeof(float), stream);

    int Npair = N >> 1;
    scatter_k    <<<(Npair + 255) / 256, 256, 0, stream>>>(
        (const float2*)feats, (const int4*)coords, grid, idxg, Npair, N);
    stats_dense_k<<<1024, 256, 0, stream>>>(grid, idxg, stats);
    finalize_k   <<<1, 64, 0, stream>>>(stats, weight, gamma, beta, scale, shift, N);
    out_point_k  <<<(N + 63) / 64, 256, 0, stream>>>(
        grid, (const int2*)coords, weight, scale, shift, out, N);
}